// Round 2
// baseline (6624.268 us; speedup 1.0000x reference)
//
#include <hip/hip_runtime.h>

#define NUM_VOXELS     1000000
#define N_POINTS       1500000
#define TOTAL_PROP_PTS 1000000
#define NUM_PROPOSALS  2048
#define IN_CH          134
#define M_OUT          16
#define NCH2           (IN_CH / 2)     // 67 float2 chunks per 536 B row

// ---------------------------------------------------------------------------
// v3: single fused kernel. feats = relu(A@W) is never materialized.
//
// Rationale (r1 post-mortem): K1's 64 MB feats write + K2's 64 MB random
// re-read are pure overhead -- feats is not an output, and the per-voxel
// compute (134x16 FMA) is only 4.3 GFLOP total (27 us of VALU). Fusing
// trades {536 MB streaming read + 64 MB write + 64 MB random read} for
// {~600 MB random 536 B-row reads}, deletes a launch, and puts the FMAs
// under the memory latency we were already paying in K2's gather.
//
// Structure: one block per proposal (grid 2048, 256 thr). W (134x16 f32,
// 8.6 KB) is preloaded to LDS; all lanes read the same W element per step
// -> uniform address -> broadcast, bank-conflict-free. Each thread owns
// points t0+tid, +256, ... ; per point it reads its voxel row as 67
// float2 (v*134 is 8 B-aligned only -- float4 would be UB/misaligned),
// grouped 8-at-a-time into a statically-indexed reg buffer so 8 global
// loads are in flight per group. The pidx->p2v index chain for iteration
// i+1 is issued before iteration i's row gather (pipeline from v2-K2).
// Epilogue: relu per point into proposal acc, shfl+LDS block reduce.
// out layout (f32): [P*16 means][P batchId][P ones]
// ---------------------------------------------------------------------------
__global__ __launch_bounds__(256) void k_fused(
    const float* __restrict__ A,         // [NUM_VOXELS][134]
    const float* __restrict__ W,         // [134][16]
    const int*   __restrict__ p2v,       // [N_POINTS]
    const int*   __restrict__ prop_idx,  // [T][2], col 1 = point index
    const int*   __restrict__ offsets,   // [P+1]
    const int*   __restrict__ locs,      // [N_POINTS][4], col 0 = batch id
    float*       __restrict__ out)
{
    __shared__ float Wl[IN_CH * M_OUT];  // 8.6 KB
    __shared__ float red[4][M_OUT];

    const int s   = blockIdx.x;
    const int tid = threadIdx.x;

    // cooperative W preload (2144 floats / 256 thr = 9 iters)
    for (int i = tid; i < IN_CH * M_OUT; i += 256) Wl[i] = W[i];
    __syncthreads();

    const int t0 = offsets[s];
    const int t1 = offsets[s + 1];
    const int2* pidx2 = (const int2*)prop_idx;

    float acc[M_OUT];
#pragma unroll
    for (int c = 0; c < M_OUT; ++c) acc[c] = 0.f;

    int t = t0 + tid;
    bool have = (t < t1);
    int v = 0;
    if (have) v = p2v[pidx2[t].y];       // head of the index pipeline

    while (have) {
        // issue next iteration's index chain before this row's gather
        const int  tn     = t + 256;
        const bool have_n = (tn < t1);
        int vn = 0;
        if (have_n) vn = p2v[pidx2[tn].y];

        const float2* row = (const float2*)(A + (size_t)v * IN_CH);

        float pt[M_OUT];
#pragma unroll
        for (int c = 0; c < M_OUT; ++c) pt[c] = 0.f;

        float2 abuf[8];                  // statically indexed -> registers
        // 8 groups x 8 float2 = 64 chunks = cols 0..127
#pragma unroll
        for (int g = 0; g < 8; ++g) {
#pragma unroll
            for (int j = 0; j < 8; ++j)  // 8 loads in flight per group
                abuf[j] = row[g * 8 + j];
#pragma unroll
            for (int j = 0; j < 8; ++j) {
                const int k = g * 16 + 2 * j;
                const float* w0 = &Wl[k * M_OUT];
#pragma unroll
                for (int c = 0; c < M_OUT; ++c)
                    pt[c] = fmaf(abuf[j].x, w0[c], pt[c]);
#pragma unroll
                for (int c = 0; c < M_OUT; ++c)
                    pt[c] = fmaf(abuf[j].y, w0[M_OUT + c], pt[c]);
            }
        }
        // tail: chunks 64..66 = cols 128..133
#pragma unroll
        for (int j = 0; j < 3; ++j) abuf[j] = row[64 + j];
#pragma unroll
        for (int j = 0; j < 3; ++j) {
            const int k = 128 + 2 * j;
            const float* w0 = &Wl[k * M_OUT];
#pragma unroll
            for (int c = 0; c < M_OUT; ++c)
                pt[c] = fmaf(abuf[j].x, w0[c], pt[c]);
#pragma unroll
            for (int c = 0; c < M_OUT; ++c)
                pt[c] = fmaf(abuf[j].y, w0[M_OUT + c], pt[c]);
        }

        // relu + accumulate into proposal sum
#pragma unroll
        for (int c = 0; c < M_OUT; ++c) acc[c] += fmaxf(pt[c], 0.f);

        v = vn; t = tn; have = have_n;
    }

    // wave-level reduction (width 64)
#pragma unroll
    for (int c = 0; c < M_OUT; ++c) {
#pragma unroll
        for (int off = 32; off > 0; off >>= 1)
            acc[c] += __shfl_down(acc[c], off, 64);
    }

    const int lane = tid & 63, wv = tid >> 6;
    if (lane == 0) {
#pragma unroll
        for (int c = 0; c < M_OUT; ++c) red[wv][c] = acc[c];
    }
    __syncthreads();

    if (tid < M_OUT) {
        const float sum = red[0][tid] + red[1][tid] + red[2][tid] + red[3][tid];
        const float cnt = (float)(t1 - t0);
        out[s * M_OUT + tid] = sum / fmaxf(cnt, 1.f);
    }
    if (tid == 0) {
        // offsets[s] < T for s < P, so this index is always valid
        const int p = prop_idx[2 * t0 + 1];
        out[NUM_PROPOSALS * M_OUT + s]                 = (float)locs[4 * p];
        out[NUM_PROPOSALS * M_OUT + NUM_PROPOSALS + s] = 1.0f;
    }
}

// ---------------------------------------------------------------------------
// NOTE (timing model, r1): dur_us includes ~330 us of harness ws-poison fill
// (fillBufferAligned, 2.14 GB WRITE = 2 GiB ws, once per timed iteration)
// plus input restores. Kernel-attributable budget is dur_us minus ~550-600.
// Fused roofline: ~600 MB of random 536 B row-gathers at 6.3 TB/s ~= 100 us
// + ~15 us index traffic. If dur_us doesn't move this round, the window is
// harness-dominated and the kernel side is at its floor.
// ---------------------------------------------------------------------------
extern "C" void kernel_launch(void* const* d_in, const int* in_sizes, int n_in,
                              void* d_out, int out_size, void* d_ws, size_t ws_size,
                              hipStream_t stream)
{
    const float* A    = (const float*)d_in[0];   // voxel_feats [1M][134]
    const float* W    = (const float*)d_in[1];   // [134][16]
    const int*   p2v  = (const int*)  d_in[2];   // [1.5M]
    const int*   pidx = (const int*)  d_in[3];   // [1M][2]
    const int*   offs = (const int*)  d_in[4];   // [2049]
    const int*   locs = (const int*)  d_in[5];   // [1.5M][4]
    float*       out  = (float*)      d_out;     // 36864 f32

    (void)d_ws; (void)ws_size;                   // workspace no longer needed

    k_fused<<<NUM_PROPOSALS, 256, 0, stream>>>(A, W, p2v, pidx, offs, locs, out);
}

// Round 3
// 777.910 us; speedup vs baseline: 8.5155x; 8.5155x over previous
//
#include <hip/hip_runtime.h>

#define NUM_VOXELS     1000000
#define N_POINTS       1500000
#define TOTAL_PROP_PTS 1000000
#define NUM_PROPOSALS  2048
#define IN_CH          134
#define M_OUT          16

#define G1 ((NUM_VOXELS + 255) / 256)      // gemm blocks (3907)
#define GV ((TOTAL_PROP_PTS + 255) / 256)  // vt-precompute blocks (3907)

// ---------------------------------------------------------------------------
// v4 (r2 post-mortem: fusion was wrong -- feats[64MB] fits L3, A[536MB]
// doesn't; and the fused kernel spilled at VGPR=256 -> 2.7GB scratch WRITE).
// Back to two-pass through the L3-resident intermediate, plus:
//
// K1' = gemm blocks (blockIdx < G1) + vt-precompute blocks appended.
//   vt[t] = p2v[prop_idx[t].y] is latency-bound index chasing; it rides in
//   K1's launch because K1 is BW-bound (VALU + latency slots idle). This
//   removes 2 levels of the dependent chain from every K2 iteration and
//   costs no extra launch.
// K2' = 4 lanes per point. One float4 instruction covers 16 points x 64 B
//   -> ~1 memory transaction per point instead of 6 (previously: 4 separate
//   16B same-row loads from ONE lane never coalesce, + pidx + p2v).
//   Chain is now coalesced vt-load -> gather, pipelined 1-ahead.
//
// ws layout: [0,64MB) feats, [64MB,68MB) vt. (2GiB poison fill runs
// unconditionally per r2 evidence -- using ws is free.)
// out layout (f32): [P*16 means][P batchId][P ones]
// ---------------------------------------------------------------------------
__global__ __launch_bounds__(256, 4) void k_gemm_relu_vt(
    const float* __restrict__ A, const float* __restrict__ W,
    const int* __restrict__ p2v, const int* __restrict__ prop_idx,
    float* __restrict__ feats, int* __restrict__ vt)
{
    // ---------------- vt-precompute blocks ----------------
    if (blockIdx.x >= G1) {
        const int t = (blockIdx.x - G1) * 256 + threadIdx.x;
        if (t < TOTAL_PROP_PTS) {
            const int2* pidx2 = (const int2*)prop_idx;
            vt[t] = p2v[pidx2[t].y];
        }
        return;
    }

    // ---------------- gemm blocks (v2 K1, verified) ----------------
    __shared__ float lds[4][64 * 33];
    const int wave = threadIdx.x >> 6;
    const int lane = threadIdx.x & 63;
    const int v0   = blockIdx.x * 256 + wave * 64;
    if (v0 >= NUM_VOXELS) return;                    // NUM_VOXELS % 64 == 0

    float* chunk = lds[wave];

    // K-tail cols 128..133 as 3x float2 (8B aligned), latency hidden
    const float* myrow = A + (size_t)(v0 + lane) * IN_CH;
    const float2 tl0 = *(const float2*)(myrow + 128);
    const float2 tl1 = *(const float2*)(myrow + 130);
    const float2 tl2 = *(const float2*)(myrow + 132);

    const int srow = lane >> 4;
    const int scol = (lane & 15) * 2;
    const float* sbase = A + (size_t)(v0 + srow) * IN_CH + scol;

    float2 buf[16];
#pragma unroll
    for (int j = 0; j < 16; ++j)                     // prefetch chunk 0
        buf[j] = *(const float2*)(sbase + (size_t)j * 4 * IN_CH);

    float acc[M_OUT];
#pragma unroll
    for (int c = 0; c < M_OUT; ++c) acc[c] = 0.f;

#pragma unroll
    for (int cidx = 0; cidx < 4; ++cidx) {
        const int kc = cidx * 32;
#pragma unroll
        for (int j = 0; j < 16; ++j) {
            const int row = j * 4 + srow;
            *(float2*)&chunk[row * 33 + scol] = buf[j];
        }
        if (cidx < 3) {
            const float* nb = sbase + kc + 32;
#pragma unroll
            for (int j = 0; j < 16; ++j)
                buf[j] = *(const float2*)(nb + (size_t)j * 4 * IN_CH);
        }
        const float* wbase = W + kc * M_OUT;
#pragma unroll
        for (int kk = 0; kk < 32; ++kk) {
            const float a = chunk[lane * 33 + kk];
            const float* wr = wbase + kk * M_OUT;
#pragma unroll
            for (int c = 0; c < M_OUT; ++c) acc[c] = fmaf(a, wr[c], acc[c]);
        }
    }
    {
        const float* wr = W + 128 * M_OUT;
#pragma unroll
        for (int c = 0; c < M_OUT; ++c) {
            float v = fmaf(tl0.x, wr[0 * M_OUT + c], acc[c]);
            v = fmaf(tl0.y, wr[1 * M_OUT + c], v);
            v = fmaf(tl1.x, wr[2 * M_OUT + c], v);
            v = fmaf(tl1.y, wr[3 * M_OUT + c], v);
            v = fmaf(tl2.x, wr[4 * M_OUT + c], v);
            acc[c] = fmaf(tl2.y, wr[5 * M_OUT + c], v);
        }
    }
    float4* orow = (float4*)(feats + (size_t)(v0 + lane) * M_OUT);
#pragma unroll
    for (int q = 0; q < 4; ++q) {
        float4 o;
        o.x = fmaxf(acc[q * 4 + 0], 0.f);
        o.y = fmaxf(acc[q * 4 + 1], 0.f);
        o.z = fmaxf(acc[q * 4 + 2], 0.f);
        o.w = fmaxf(acc[q * 4 + 3], 0.f);
        orow[q] = o;
    }
}

// ---------------------------------------------------------------------------
// K2': one block per proposal, 4 lanes per point.
//   group g = tid>>2 (0..63 points per pass), q = tid&3 (channel quarter).
//   Gather instr: lanes g*4+q load feats[v[g]*16 + q*4 ..+4) -> 16 points
//   x 64 B per wave-instruction, ~1 transaction per point.
// ---------------------------------------------------------------------------
__global__ __launch_bounds__(256) void k_propmean(
    const float* __restrict__ feats,
    const int*   __restrict__ vt,        // [T] precomputed voxel per point
    const int*   __restrict__ prop_idx,  // [T][2] (for batchId only)
    const int*   __restrict__ offsets,   // [P+1]
    const int*   __restrict__ locs,      // [N_POINTS][4], col 0 = batch id
    float*       __restrict__ out)
{
    const int s   = blockIdx.x;
    const int tid = threadIdx.x;
    const int t0  = offsets[s];
    const int t1  = offsets[s + 1];
    const int g   = tid >> 2;
    const int q   = tid & 3;

    float a0 = 0.f, a1 = 0.f, a2 = 0.f, a3 = 0.f;

    int t = t0 + g;
    int v = (t < t1) ? vt[t] : -1;       // coalesced (4 lanes broadcast)

    for (int base = t0; base < t1; base += 64) {
        const int tn = t + 64;
        const int vn = (tn < t1) ? vt[tn] : -1;   // next pass, in flight now

        if (v >= 0) {
            const float4 f = *(const float4*)(feats + (size_t)v * M_OUT + q * 4);
            a0 += f.x; a1 += f.y; a2 += f.z; a3 += f.w;
        }
        v = vn; t = tn;
    }

    // reduce across groups: lanes with equal q hold the same channel quarter
#pragma unroll
    for (int off = 4; off < 64; off <<= 1) {
        a0 += __shfl_down(a0, off, 64);
        a1 += __shfl_down(a1, off, 64);
        a2 += __shfl_down(a2, off, 64);
        a3 += __shfl_down(a3, off, 64);
    }
    // lanes 0..3 of each wave: channel quarter q totals

    __shared__ float red[4][4][4];       // [wave][q][elem]
    const int lane = tid & 63, wv = tid >> 6;
    if (lane < 4) {
        red[wv][lane][0] = a0; red[wv][lane][1] = a1;
        red[wv][lane][2] = a2; red[wv][lane][3] = a3;
    }
    __syncthreads();

    if (tid < M_OUT) {                   // channel c = tid = (tid>>2)*4 + (tid&3)
        const float sum = red[0][tid >> 2][tid & 3] + red[1][tid >> 2][tid & 3]
                        + red[2][tid >> 2][tid & 3] + red[3][tid >> 2][tid & 3];
        const float cnt = (float)(t1 - t0);
        out[s * M_OUT + tid] = sum / fmaxf(cnt, 1.f);
    }
    if (tid == 0) {
        const int p = prop_idx[2 * t0 + 1];   // offsets[s] < T always
        out[NUM_PROPOSALS * M_OUT + s]                 = (float)locs[4 * p];
        out[NUM_PROPOSALS * M_OUT + NUM_PROPOSALS + s] = 1.0f;
    }
}

// ---------------------------------------------------------------------------
// Timing model (r2 calibration): harness overhead ~= 526 us/iter (2GiB ws
// poison fill ~330 + restores/gaps ~196), runs regardless of ws use.
// v2 kernel-attributable ~= 248 us. Floors: K1 ~95 us (600 MB stream),
// K2' ~20-40 us (1M x ~1.1 transactions, feats L3-resident).
// ---------------------------------------------------------------------------
extern "C" void kernel_launch(void* const* d_in, const int* in_sizes, int n_in,
                              void* d_out, int out_size, void* d_ws, size_t ws_size,
                              hipStream_t stream)
{
    const float* A    = (const float*)d_in[0];   // voxel_feats [1M][134]
    const float* W    = (const float*)d_in[1];   // [134][16]
    const int*   p2v  = (const int*)  d_in[2];   // [1.5M]
    const int*   pidx = (const int*)  d_in[3];   // [1M][2]
    const int*   offs = (const int*)  d_in[4];   // [2049]
    const int*   locs = (const int*)  d_in[5];   // [1.5M][4]
    float*       out  = (float*)      d_out;     // 36864 f32

    float* feats = (float*)d_ws;                              // 64 MB
    int*   vt    = (int*)((char*)d_ws + (size_t)64 * 1024 * 1024); // 4 MB

    k_gemm_relu_vt<<<G1 + GV, 256, 0, stream>>>(A, W, p2v, pidx, feats, vt);
    k_propmean<<<NUM_PROPOSALS, 256, 0, stream>>>(feats, vt, pidx, offs, locs, out);
}